// Round 3
// baseline (393.616 us; speedup 1.0000x reference)
//
#include <hip/hip_runtime.h>
#include <stdint.h>

#define B_ROWS 4096
#define N_ROWS 8192
#define D_DIM  1024
#define NBLK   64                       // 8192 / 128 tiles per dim
#define NTRI   (NBLK * (NBLK + 1) / 2)  // 2080 upper-triangular tiles

typedef __attribute__((ext_vector_type(8))) short bf16x8;
typedef __attribute__((ext_vector_type(4))) float f32x4;

// round-to-nearest-even f32 -> bf16
static __device__ __forceinline__ unsigned short f2bf(float f) {
  uint32_t u = __float_as_uint(f);
  u += 0x7fff + ((u >> 16) & 1);
  return (unsigned short)(u >> 16);
}

// One wave per row: L2-normalize, cast to bf16, zero rowsum (+ctr).
__global__ __launch_bounds__(256) void normalize_kernel(
    const float* __restrict__ f1, const float* __restrict__ f2,
    unsigned short* __restrict__ F, float* __restrict__ rowsum,
    unsigned int* __restrict__ ctr) {
  const int wv   = threadIdx.x >> 6;
  const int lane = threadIdx.x & 63;
  const int row  = blockIdx.x * 4 + wv;
  const float* src = (row < B_ROWS) ? (f1 + (size_t)row * D_DIM)
                                    : (f2 + (size_t)(row - B_ROWS) * D_DIM);
  float4 v[4];
  float ss = 0.0f;
#pragma unroll
  for (int r = 0; r < 4; ++r) {
    v[r] = ((const float4*)src)[lane + 64 * r];
    ss += v[r].x * v[r].x + v[r].y * v[r].y + v[r].z * v[r].z + v[r].w * v[r].w;
  }
#pragma unroll
  for (int m = 1; m < 64; m <<= 1) ss += __shfl_xor(ss, m, 64);
  const float invn = 1.0f / fmaxf(sqrtf(ss), 1e-12f);
  ushort4* dst = (ushort4*)(F + (size_t)row * D_DIM);
#pragma unroll
  for (int r = 0; r < 4; ++r) {
    ushort4 o;
    o.x = f2bf(v[r].x * invn); o.y = f2bf(v[r].y * invn);
    o.z = f2bf(v[r].z * invn); o.w = f2bf(v[r].w * invn);
    dst[lane + 64 * r] = o;
  }
  if (lane == 0) rowsum[row] = 0.0f;
  if (row == 0 && lane == 0) *ctr = 0u;
}

// Barrier-free fused Gram-GEMM + exp-sum epilogue + fused finalize.
// Upper-triangular 128x128 tiles; 4 waves/block, each wave a 64x64 subtile
// via 4x4 grid of 16x16x32 bf16 MFMA. Fragments loaded DIRECTLY from
// row-major global F (no LDS, no __syncthreads in the K loop): the MFMA
// A/B layout (row = l16, k = q*8 + j, 16B contiguous per lane) is exactly
// a strided global_load_dwordx4. All 32 K-substeps use immediate offsets.
__global__ __launch_bounds__(256, 3) void simloss_kernel(
    const unsigned short* __restrict__ F, float* __restrict__ rowsum,
    float* __restrict__ pos, unsigned int* __restrict__ ctr,
    float* __restrict__ out) {
  // decode linear block id -> (bi, bj), bi <= bj (upper triangle)
  int rem = blockIdx.x;
  int bi = 0;
  while (rem >= NBLK - bi) { rem -= NBLK - bi; ++bi; }
  const int bj = bi + rem;

  const int tid  = threadIdx.x;
  const int lane = tid & 63;
  const int wv   = __builtin_amdgcn_readfirstlane(tid >> 6);
  const int waveRow = wv >> 1;
  const int waveCol = wv & 1;
  const int q   = lane >> 4;   // quad within wave
  const int l16 = lane & 15;

  const int iBase = bi * 128;
  const int jBase = bj * 128;

  // per-lane fragment stream base pointers (byte addresses)
  const char* Fb = (const char*)F;
  const char* pA[4];
  const char* pB[4];
#pragma unroll
  for (int mi = 0; mi < 4; ++mi)
    pA[mi] = Fb + ((size_t)(iBase + waveRow * 64 + mi * 16 + l16) * D_DIM + q * 8) * 2;
#pragma unroll
  for (int ni = 0; ni < 4; ++ni)
    pB[ni] = Fb + ((size_t)(jBase + waveCol * 64 + ni * 16 + l16) * D_DIM + q * 8) * 2;

  f32x4 acc[4][4];
#pragma unroll
  for (int a = 0; a < 4; ++a)
#pragma unroll
    for (int b = 0; b < 4; ++b) acc[a][b] = (f32x4){0.f, 0.f, 0.f, 0.f};

  // K loop: 32 substeps of k=32, fully unrolled, immediate byte offsets s*64.
#pragma unroll
  for (int s = 0; s < 32; ++s) {
    bf16x8 af[4], bfr[4];
#pragma unroll
    for (int mi = 0; mi < 4; ++mi) af[mi]  = *(const bf16x8*)(pA[mi] + s * 64);
#pragma unroll
    for (int ni = 0; ni < 4; ++ni) bfr[ni] = *(const bf16x8*)(pB[ni] + s * 64);
#pragma unroll
    for (int mi = 0; mi < 4; ++mi)
#pragma unroll
      for (int ni = 0; ni < 4; ++ni)
        acc[mi][ni] = __builtin_amdgcn_mfma_f32_16x16x32_bf16(
            af[mi], bfr[ni], acc[mi][ni], 0, 0, 0);
  }

  // ---- epilogue ----
  // sim = 10*dot; e = exp(sim-10) excluding diagonal.
  // Row-reduce -> rowsum[i]; off-diag tiles also column-reduce -> rowsum[j].
  const bool offdiag = (bi != bj);
  float colAcc[4] = {0.f, 0.f, 0.f, 0.f};

#pragma unroll
  for (int mi = 0; mi < 4; ++mi) {
#pragma unroll
    for (int reg = 0; reg < 4; ++reg) {
      const int i = iBase + waveRow * 64 + mi * 16 + q * 4 + reg;
      float s = 0.0f;
#pragma unroll
      for (int ni = 0; ni < 4; ++ni) {
        const int j = jBase + waveCol * 64 + ni * 16 + l16;
        const float sim = acc[mi][ni][reg] * 10.0f;
        const float e = (j == i) ? 0.0f : __expf(sim - 10.0f);
        s += e;
        colAcc[ni] += e;
        if (i < B_ROWS && j == i + B_ROWS) atomicExch(&pos[i], sim);
      }
#pragma unroll
      for (int m = 1; m < 16; m <<= 1) s += __shfl_xor(s, m, 64);
      if (l16 == 0) atomicAdd(&rowsum[i], s);
    }
  }

  if (offdiag) {
#pragma unroll
    for (int ni = 0; ni < 4; ++ni) {
      float c = colAcc[ni];
#pragma unroll
      for (int m = 16; m < 64; m <<= 1) c += __shfl_xor(c, m, 64);
      if (q == 0) {
        const int j = jBase + waveCol * 64 + ni * 16 + l16;
        atomicAdd(&rowsum[j], c);
      }
    }
  }

  // ---- fused finalize: last block to finish computes the loss ----
  __syncthreads();  // drain this block's atomics (per-wave vmcnt(0) at barrier)
  __shared__ unsigned int lastFlag;
  if (tid == 0) {
    __threadfence();  // release: our updates visible before counter bump
    const unsigned int old = atomicAdd(ctr, 1u);
    lastFlag = (old == (unsigned int)(NTRI - 1)) ? 1u : 0u;
  }
  __syncthreads();
  if (lastFlag) {
    __threadfence();  // acquire: see all blocks' rowsum/pos updates
    float a = 0.0f;
    for (int i = tid; i < N_ROWS; i += 256)
      a += __logf(rowsum[i]) + 10.0f - pos[i & (B_ROWS - 1)];
#pragma unroll
    for (int m = 1; m < 64; m <<= 1) a += __shfl_xor(a, m, 64);
    __shared__ float red[4];
    if ((tid & 63) == 0) red[tid >> 6] = a;
    __syncthreads();
    if (tid == 0) out[0] = (red[0] + red[1] + red[2] + red[3]) * (1.0f / N_ROWS);
  }
}

extern "C" void kernel_launch(void* const* d_in, const int* in_sizes, int n_in,
                              void* d_out, int out_size, void* d_ws, size_t ws_size,
                              hipStream_t stream) {
  const float* f1 = (const float*)d_in[0];
  const float* f2 = (const float*)d_in[1];
  unsigned short* F = (unsigned short*)d_ws;                          // 16 MiB bf16 normalized features
  float* rowsum = (float*)((char*)d_ws + (size_t)N_ROWS * D_DIM * 2); // 32 KiB
  float* pos    = rowsum + N_ROWS;                                    // 16 KiB (i < B_ROWS)
  unsigned int* ctr = (unsigned int*)(pos + B_ROWS);                  // 4 B completion counter
  float* out    = (float*)d_out;

  hipLaunchKernelGGL(normalize_kernel, dim3(N_ROWS / 4), dim3(256), 0, stream,
                     f1, f2, F, rowsum, ctr);
  hipLaunchKernelGGL(simloss_kernel, dim3(NTRI), dim3(256), 0, stream,
                     F, rowsum, pos, ctr, out);
}

// Round 4
// 239.683 us; speedup vs baseline: 1.6422x; 1.6422x over previous
//
#include <hip/hip_runtime.h>
#include <stdint.h>

#define B_ROWS 4096
#define N_ROWS 8192
#define D_DIM  1024
#define BK     32
#define NBLK   64                       // 8192 / 128 tiles per dim
#define NTRI   (NBLK * (NBLK + 1) / 2)  // 2080 upper-triangular tiles

typedef __attribute__((ext_vector_type(8))) short bf16x8;
typedef __attribute__((ext_vector_type(4))) float f32x4;

// round-to-nearest-even f32 -> bf16
static __device__ __forceinline__ unsigned short f2bf(float f) {
  uint32_t u = __float_as_uint(f);
  u += 0x7fff + ((u >> 16) & 1);
  return (unsigned short)(u >> 16);
}

static __device__ __forceinline__ void async_copy16(const unsigned short* g, unsigned short* l) {
  __builtin_amdgcn_global_load_lds(
      (const __attribute__((address_space(1))) unsigned int*)g,
      (__attribute__((address_space(3))) unsigned int*)l, 16, 0, 0);
}

// One wave per row: L2-normalize, cast to bf16, zero rowsum (+ctr).
__global__ __launch_bounds__(256) void normalize_kernel(
    const float* __restrict__ f1, const float* __restrict__ f2,
    unsigned short* __restrict__ F, float* __restrict__ rowsum,
    unsigned int* __restrict__ ctr) {
  const int wv   = threadIdx.x >> 6;
  const int lane = threadIdx.x & 63;
  const int row  = blockIdx.x * 4 + wv;
  const float* src = (row < B_ROWS) ? (f1 + (size_t)row * D_DIM)
                                    : (f2 + (size_t)(row - B_ROWS) * D_DIM);
  float4 v[4];
  float ss = 0.0f;
#pragma unroll
  for (int r = 0; r < 4; ++r) {
    v[r] = ((const float4*)src)[lane + 64 * r];
    ss += v[r].x * v[r].x + v[r].y * v[r].y + v[r].z * v[r].z + v[r].w * v[r].w;
  }
#pragma unroll
  for (int m = 1; m < 64; m <<= 1) ss += __shfl_xor(ss, m, 64);
  const float invn = 1.0f / fmaxf(sqrtf(ss), 1e-12f);
  ushort4* dst = (ushort4*)(F + (size_t)row * D_DIM);
#pragma unroll
  for (int r = 0; r < 4; ++r) {
    ushort4 o;
    o.x = f2bf(v[r].x * invn); o.y = f2bf(v[r].y * invn);
    o.z = f2bf(v[r].z * invn); o.w = f2bf(v[r].w * invn);
    dst[lane + 64 * r] = o;
  }
  if (lane == 0) rowsum[row] = 0.0f;
  if (row == 0 && lane == 0) *ctr = 0u;
}

// Fused Gram-GEMM + exp-sum epilogue + fused finalize, upper-triangular
// block grid, PING-PONG double-buffered LDS (BK=32, 2x16KB = 32KB):
// issue global_load_lds for tile k+1 right after the barrier, compute
// tile k, barrier (vmcnt(0) drain then covers loads that had a full
// compute phase in flight). 128x128 tile / block, 4 waves, each wave
// 64x64 via 4x4 grid of 16x16x32 bf16 MFMA.
// LDS chunk swizzle: chunk ch holds row r=ch>>2, k-chunk c=(ch&3)^((r>>1)&3);
// reader (quad q, row r) uses ch = r*4 + (q ^ ((r>>1)&3)) -> 2-way max
// bank aliasing (free).
__global__ __launch_bounds__(256) void simloss_kernel(
    const unsigned short* __restrict__ F, float* __restrict__ rowsum,
    float* __restrict__ pos, unsigned int* __restrict__ ctr,
    float* __restrict__ out) {
  __shared__ unsigned short lA[2][128 * BK];
  __shared__ unsigned short lB[2][128 * BK];

  // XCD swizzle: give each XCD (b%8) a contiguous triangle band so the
  // A-tile rows stay hot in its private L2. 2080 = 8 * 260.
  const int b    = (int)blockIdx.x;
  const int tile = (b & 7) * (NTRI / 8) + (b >> 3);

  // decode tile -> (bi, bj), bi <= bj (upper triangle, row-major)
  int rem = tile;
  int bi = 0;
  while (rem >= NBLK - bi) { rem -= NBLK - bi; ++bi; }
  const int bj = bi + rem;

  const int tid  = threadIdx.x;
  const int lane = tid & 63;
  const int wv   = __builtin_amdgcn_readfirstlane(tid >> 6);
  const int waveRow = wv >> 1;
  const int waveCol = wv & 1;
  const int q   = lane >> 4;   // quad within wave
  const int l16 = lane & 15;

  const int iBase = bi * 128;
  const int jBase = bj * 128;
  const unsigned short* Abase = F + (size_t)iBase * D_DIM;
  const unsigned short* Bbase = F + (size_t)jBase * D_DIM;

  f32x4 acc[4][4];
#pragma unroll
  for (int a = 0; a < 4; ++a)
#pragma unroll
    for (int c = 0; c < 4; ++c) acc[a][c] = (f32x4){0.f, 0.f, 0.f, 0.f};

  // precompute this thread's two staging chunk ids and global offsets
  int s_lc[2]; size_t s_go[2];
#pragma unroll
  for (int c2 = 0; c2 < 2; ++c2) {
    const int lc = c2 * 256 + wv * 64 + lane;
    const int r  = lc >> 2;
    const int c  = (lc & 3) ^ ((lc >> 3) & 3);
    s_lc[c2] = lc;
    s_go[c2] = (size_t)r * D_DIM + c * 8;
  }
  // this lane's 8 ds_read chunk offsets (elements), fixed across iters
  int rdA[4], rdB[4];
#pragma unroll
  for (int mi = 0; mi < 4; ++mi) {
    const int r = waveRow * 64 + mi * 16 + l16;
    rdA[mi] = (r * 4 + (q ^ ((r >> 1) & 3))) * 8;
  }
#pragma unroll
  for (int ni = 0; ni < 4; ++ni) {
    const int r = waveCol * 64 + ni * 16 + l16;
    rdB[ni] = (r * 4 + (q ^ ((r >> 1) & 3))) * 8;
  }

  // prologue: stage tile 0 into buffer 0
#pragma unroll
  for (int c2 = 0; c2 < 2; ++c2) {
    async_copy16(Abase + s_go[c2], &lA[0][s_lc[c2] * 8]);
    async_copy16(Bbase + s_go[c2], &lB[0][s_lc[c2] * 8]);
  }
  __syncthreads();

#pragma unroll 2
  for (int it = 0; it < 32; ++it) {
    const int cur = it & 1;
    if (it < 31) {
      const int nxt = cur ^ 1;
      const size_t k0 = (size_t)(it + 1) * BK;
#pragma unroll
      for (int c2 = 0; c2 < 2; ++c2) {
        async_copy16(Abase + k0 + s_go[c2], &lA[nxt][s_lc[c2] * 8]);
        async_copy16(Bbase + k0 + s_go[c2], &lB[nxt][s_lc[c2] * 8]);
      }
    }
    bf16x8 af[4], bfr[4];
#pragma unroll
    for (int mi = 0; mi < 4; ++mi) af[mi]  = *(const bf16x8*)&lA[cur][rdA[mi]];
#pragma unroll
    for (int ni = 0; ni < 4; ++ni) bfr[ni] = *(const bf16x8*)&lB[cur][rdB[ni]];
#pragma unroll
    for (int mi = 0; mi < 4; ++mi)
#pragma unroll
      for (int ni = 0; ni < 4; ++ni)
        acc[mi][ni] = __builtin_amdgcn_mfma_f32_16x16x32_bf16(
            af[mi], bfr[ni], acc[mi][ni], 0, 0, 0);
    __syncthreads();
  }

  // ---- epilogue ----
  // sim = 10*dot; e = exp(sim-10) excluding diagonal.
  // Row-reduce -> rowsum[i]; off-diag tiles also column-reduce -> rowsum[j].
  const bool offdiag = (bi != bj);
  float colAcc[4] = {0.f, 0.f, 0.f, 0.f};

#pragma unroll
  for (int mi = 0; mi < 4; ++mi) {
#pragma unroll
    for (int reg = 0; reg < 4; ++reg) {
      const int i = iBase + waveRow * 64 + mi * 16 + q * 4 + reg;
      float s = 0.0f;
#pragma unroll
      for (int ni = 0; ni < 4; ++ni) {
        const int j = jBase + waveCol * 64 + ni * 16 + l16;
        const float sim = acc[mi][ni][reg] * 10.0f;
        const float e = (j == i) ? 0.0f : __expf(sim - 10.0f);
        s += e;
        colAcc[ni] += e;
        if (i < B_ROWS && j == i + B_ROWS) pos[i] = sim;
      }
#pragma unroll
      for (int m = 1; m < 16; m <<= 1) s += __shfl_xor(s, m, 64);
      if (l16 == 0) atomicAdd(&rowsum[i], s);
    }
  }

  if (offdiag) {
#pragma unroll
    for (int ni = 0; ni < 4; ++ni) {
      float c = colAcc[ni];
#pragma unroll
      for (int m = 16; m < 64; m <<= 1) c += __shfl_xor(c, m, 64);
      if (q == 0) {
        const int j = jBase + waveCol * 64 + ni * 16 + l16;
        atomicAdd(&rowsum[j], c);
      }
    }
  }

  // ---- fused finalize: last block to finish computes the loss ----
  __syncthreads();
  __shared__ unsigned int lastFlag;
  if (tid == 0) {
    __threadfence();  // release our rowsum/pos updates
    const unsigned int old = atomicAdd(ctr, 1u);
    lastFlag = (old == (unsigned int)(NTRI - 1)) ? 1u : 0u;
  }
  __syncthreads();
  if (lastFlag) {
    __threadfence();  // acquire all blocks' updates
    float a = 0.0f;
    for (int i = tid; i < N_ROWS; i += 256)
      a += __logf(rowsum[i]) + 10.0f - pos[i & (B_ROWS - 1)];
#pragma unroll
    for (int m = 1; m < 64; m <<= 1) a += __shfl_xor(a, m, 64);
    __shared__ float red[4];
    if ((tid & 63) == 0) red[tid >> 6] = a;
    __syncthreads();
    if (tid == 0) out[0] = (red[0] + red[1] + red[2] + red[3]) * (1.0f / N_ROWS);
  }
}

extern "C" void kernel_launch(void* const* d_in, const int* in_sizes, int n_in,
                              void* d_out, int out_size, void* d_ws, size_t ws_size,
                              hipStream_t stream) {
  const float* f1 = (const float*)d_in[0];
  const float* f2 = (const float*)d_in[1];
  unsigned short* F = (unsigned short*)d_ws;                          // 16 MiB bf16 normalized features
  float* rowsum = (float*)((char*)d_ws + (size_t)N_ROWS * D_DIM * 2); // 32 KiB
  float* pos    = rowsum + N_ROWS;                                    // 16 KiB (i < B_ROWS)
  unsigned int* ctr = (unsigned int*)(pos + B_ROWS);                  // 4 B completion counter
  float* out    = (float*)d_out;

  hipLaunchKernelGGL(normalize_kernel, dim3(N_ROWS / 4), dim3(256), 0, stream,
                     f1, f2, F, rowsum, ctr);
  hipLaunchKernelGGL(simloss_kernel, dim3(NTRI), dim3(256), 0, stream,
                     F, rowsum, pos, ctr, out);
}